// Round 1
// baseline (339.882 us; speedup 1.0000x reference)
//
#include <hip/hip_runtime.h>
#include <hip/hip_bf16.h>

#define BB 8
#define NN 4096
#define CC 128
#define SCALE 0.088388347648318447f   // 128^-0.5
#define LOG2E 1.44269504088896f

typedef __attribute__((ext_vector_type(8))) short short8v;
typedef __attribute__((ext_vector_type(4))) float f32x4;

__device__ __forceinline__ short f2bf(float f) {
  unsigned u = __float_as_uint(f);
  u = (u + 0x7FFFu + ((u >> 16) & 1u)) >> 16;
  return (short)u;
}

__device__ __forceinline__ f32x4 mfma_bf16(short8v a, short8v b, f32x4 c) {
  return __builtin_amdgcn_mfma_f32_16x16x32_bf16(a, b, c, 0, 0, 0);
}

// ---------------- weight convert: wT[n][k] bf16, scale folded into wq/bq ----
__global__ __launch_bounds__(256) void convw_k(
    const float* __restrict__ wq, const float* __restrict__ wk,
    const float* __restrict__ wv, const float* __restrict__ wo,
    const float* __restrict__ bq, short* __restrict__ wT,
    float* __restrict__ bqs) {
  int gid = blockIdx.x * 256 + threadIdx.x;   // 4*16384
  int widx = gid >> 14, e = gid & 16383;
  int kk = e >> 7, n = e & 127;
  const float* src = (widx == 0) ? wq : (widx == 1) ? wk : (widx == 2) ? wv : wo;
  float v = src[kk * 128 + n];
  if (widx == 0) v *= SCALE;
  wT[widx * 16384 + n * 128 + kk] = f2bf(v);
  if (gid < 128) bqs[gid] = bq[gid] * SCALE;
}

// ---------------- groupnorm stats: one block per (b,g) ----------------------
__global__ __launch_bounds__(256) void gnstat_k(const float* __restrict__ x,
    float* __restrict__ mean, float* __restrict__ rstd) {
  int bg = blockIdx.x;                         // b*32+g
  const float* xp = x + (size_t)(bg >> 5) * NN * CC + (bg & 31) * 4;
  float s = 0.f, ss = 0.f;
  for (int n = threadIdx.x; n < NN; n += 256) {
    float4 v = *reinterpret_cast<const float4*>(xp + (size_t)n * CC);
    s  += v.x + v.y + v.z + v.w;
    ss += v.x * v.x + v.y * v.y + v.z * v.z + v.w * v.w;
  }
  #pragma unroll
  for (int m = 1; m < 64; m <<= 1) {
    s += __shfl_xor(s, m, 64);
    ss += __shfl_xor(ss, m, 64);
  }
  __shared__ float rs[4], rss[4];
  int wid = threadIdx.x >> 6;
  if ((threadIdx.x & 63) == 0) { rs[wid] = s; rss[wid] = ss; }
  __syncthreads();
  if (threadIdx.x == 0) {
    s = rs[0] + rs[1] + rs[2] + rs[3];
    ss = rss[0] + rss[1] + rss[2] + rss[3];
    float mu = s * (1.f / 16384.f);
    float var = ss * (1.f / 16384.f) - mu * mu;
    mean[bg] = mu;
    rstd[bg] = rsqrtf(var + 1e-6f);
  }
}

// ---------------- groupnorm apply -> h bf16 ---------------------------------
__global__ __launch_bounds__(256) void gnapply_k(const float* __restrict__ x,
    const float* __restrict__ mean, const float* __restrict__ rstd,
    const float* __restrict__ gsc, const float* __restrict__ gbi,
    short* __restrict__ h) {
  int idx = blockIdx.x * 256 + threadIdx.x;    // row*32 + g
  int row = idx >> 5, g = idx & 31;
  int bg = ((row >> 12) << 5) | g;
  float4 v  = *reinterpret_cast<const float4*>(x + (size_t)row * CC + g * 4);
  float4 sc = *reinterpret_cast<const float4*>(gsc + g * 4);
  float4 bi = *reinterpret_cast<const float4*>(gbi + g * 4);
  float mu = mean[bg], r = rstd[bg];
  short4 o;
  o.x = f2bf((v.x - mu) * r * sc.x + bi.x);
  o.y = f2bf((v.y - mu) * r * sc.y + bi.y);
  o.z = f2bf((v.z - mu) * r * sc.z + bi.z);
  o.w = f2bf((v.w - mu) * r * sc.w + bi.w);
  *reinterpret_cast<short4*>(h + (size_t)row * CC + g * 4) = o;
}

// ---------------- projection GEMM: out = h @ W + b --------------------------
// TRANS=0: out[row][col] bf16 ([B*N][C]).  TRANS=1: out[b][col][n] (V^T).
template <int TRANS>
__global__ __launch_bounds__(256) void proj_k(const short* __restrict__ h,
    const short* __restrict__ wT, const float* __restrict__ bias,
    short* __restrict__ out) {
  __shared__ short wlds[128][136];
  int lane = threadIdx.x & 63, wid = threadIdx.x >> 6;
  for (int i = threadIdx.x; i < 2048; i += 256) {
    int n = i >> 4, kk = (i & 15) << 3;
    *reinterpret_cast<short8v*>(&wlds[n][kk]) =
        *reinterpret_cast<const short8v*>(wT + n * 128 + kk);
  }
  int row0 = blockIdx.x * 64 + wid * 16;
  int arow = row0 + (lane & 15);
  short8v a[4];
  #pragma unroll
  for (int dt = 0; dt < 4; ++dt)
    a[dt] = *reinterpret_cast<const short8v*>(
        h + (size_t)arow * 128 + dt * 32 + ((lane >> 4) << 3));
  __syncthreads();
  f32x4 zero = {0.f, 0.f, 0.f, 0.f};
  f32x4 acc[8];
  #pragma unroll
  for (int nt = 0; nt < 8; ++nt) acc[nt] = zero;
  #pragma unroll
  for (int nt = 0; nt < 8; ++nt) {
    #pragma unroll
    for (int kk = 0; kk < 4; ++kk) {
      short8v b = *reinterpret_cast<const short8v*>(
          &wlds[nt * 16 + (lane & 15)][kk * 32 + ((lane >> 4) << 3)]);
      acc[nt] = mfma_bf16(a[kk], b, acc[nt]);
    }
  }
  #pragma unroll
  for (int nt = 0; nt < 8; ++nt) {
    #pragma unroll
    for (int r = 0; r < 4; ++r) {
      int row = row0 + ((lane >> 4) << 2) + r;
      int col = nt * 16 + (lane & 15);
      float v = acc[nt][r] + bias[col];
      if (TRANS) {
        int b_ = row >> 12, n = row & 4095;
        out[((size_t)b_ * 128 + col) * 4096 + n] = f2bf(v);
      } else {
        out[(size_t)row * 128 + col] = f2bf(v);
      }
    }
  }
}

// ---------------- output projection + bias + residual (fp32 out) ------------
__global__ __launch_bounds__(256) void projo_k(const short* __restrict__ o,
    const short* __restrict__ wT, const float* __restrict__ bias,
    const float* __restrict__ x, float* __restrict__ out) {
  __shared__ short wlds[128][136];
  int lane = threadIdx.x & 63, wid = threadIdx.x >> 6;
  for (int i = threadIdx.x; i < 2048; i += 256) {
    int n = i >> 4, kk = (i & 15) << 3;
    *reinterpret_cast<short8v*>(&wlds[n][kk]) =
        *reinterpret_cast<const short8v*>(wT + n * 128 + kk);
  }
  int row0 = blockIdx.x * 64 + wid * 16;
  int arow = row0 + (lane & 15);
  short8v a[4];
  #pragma unroll
  for (int dt = 0; dt < 4; ++dt)
    a[dt] = *reinterpret_cast<const short8v*>(
        o + (size_t)arow * 128 + dt * 32 + ((lane >> 4) << 3));
  __syncthreads();
  f32x4 zero = {0.f, 0.f, 0.f, 0.f};
  f32x4 acc[8];
  #pragma unroll
  for (int nt = 0; nt < 8; ++nt) acc[nt] = zero;
  #pragma unroll
  for (int nt = 0; nt < 8; ++nt) {
    #pragma unroll
    for (int kk = 0; kk < 4; ++kk) {
      short8v b = *reinterpret_cast<const short8v*>(
          &wlds[nt * 16 + (lane & 15)][kk * 32 + ((lane >> 4) << 3)]);
      acc[nt] = mfma_bf16(a[kk], b, acc[nt]);
    }
  }
  #pragma unroll
  for (int nt = 0; nt < 8; ++nt) {
    #pragma unroll
    for (int r = 0; r < 4; ++r) {
      int row = row0 + ((lane >> 4) << 2) + r;
      int col = nt * 16 + (lane & 15);
      out[(size_t)row * 128 + col] =
          acc[nt][r] + bias[col] + x[(size_t)row * 128 + col];
    }
  }
}

// ---------------- flash attention -------------------------------------------
// grid = B * (N/64); 4 waves/block, each wave owns 16 q-rows.
__global__ __launch_bounds__(256) void attn_k(const short* __restrict__ q,
    const short* __restrict__ k, const short* __restrict__ vt,
    short* __restrict__ o) {
  __shared__ short klds[64][136];
  __shared__ short vlds[128][72];
  __shared__ short plds[4][16][72];
  int b = blockIdx.x >> 6, qt = blockIdx.x & 63;
  int lane = threadIdx.x & 63, wid = threadIdx.x >> 6;
  const short* qb = q + (size_t)b * NN * CC;
  const short* kb = k + (size_t)b * NN * CC;
  const short* vb = vt + (size_t)b * CC * NN;
  int qrow = qt * 64 + wid * 16;

  short8v qf[4];
  #pragma unroll
  for (int dt = 0; dt < 4; ++dt)
    qf[dt] = *reinterpret_cast<const short8v*>(
        qb + (size_t)(qrow + (lane & 15)) * CC + dt * 32 + ((lane >> 4) << 3));

  f32x4 zero = {0.f, 0.f, 0.f, 0.f};
  f32x4 oacc[8];
  #pragma unroll
  for (int nt = 0; nt < 8; ++nt) oacc[nt] = zero;
  float mrow[4], lrow[4];
  #pragma unroll
  for (int r = 0; r < 4; ++r) { mrow[r] = -1e30f; lrow[r] = 0.f; }

  for (int kv = 0; kv < NN; kv += 64) {
    __syncthreads();
    for (int i = threadIdx.x; i < 1024; i += 256) {
      int r = i >> 4, cg = (i & 15) << 3;
      *reinterpret_cast<short8v*>(&klds[r][cg]) =
          *reinterpret_cast<const short8v*>(kb + (size_t)(kv + r) * CC + cg);
    }
    for (int i = threadIdx.x; i < 1024; i += 256) {
      int d = i >> 3, jg = (i & 7) << 3;
      *reinterpret_cast<short8v*>(&vlds[d][jg]) =
          *reinterpret_cast<const short8v*>(vb + (size_t)d * NN + kv + jg);
    }
    __syncthreads();

    // S = Q K^T  (16 x 64 per wave)
    f32x4 s[4];
    #pragma unroll
    for (int jt = 0; jt < 4; ++jt) s[jt] = zero;
    #pragma unroll
    for (int jt = 0; jt < 4; ++jt) {
      #pragma unroll
      for (int dt = 0; dt < 4; ++dt) {
        short8v kf = *reinterpret_cast<const short8v*>(
            &klds[jt * 16 + (lane & 15)][dt * 32 + ((lane >> 4) << 3)]);
        s[jt] = mfma_bf16(qf[dt], kf, s[jt]);
      }
    }

    // online softmax (rows = qrow + (lane>>4)*4 + r, cols across 16 lanes)
    float pm[4], corr[4], ps[4];
    #pragma unroll
    for (int r = 0; r < 4; ++r) {
      pm[r] = fmaxf(fmaxf(s[0][r], s[1][r]), fmaxf(s[2][r], s[3][r]));
      #pragma unroll
      for (int m = 1; m < 16; m <<= 1) pm[r] = fmaxf(pm[r], __shfl_xor(pm[r], m, 64));
      float mn = fmaxf(mrow[r], pm[r]);
      corr[r] = exp2f((mrow[r] - mn) * LOG2E);
      mrow[r] = mn;
      ps[r] = 0.f;
    }
    #pragma unroll
    for (int jt = 0; jt < 4; ++jt) {
      #pragma unroll
      for (int r = 0; r < 4; ++r) {
        float p = exp2f((s[jt][r] - mrow[r]) * LOG2E);
        s[jt][r] = p;
        ps[r] += p;
      }
    }
    #pragma unroll
    for (int r = 0; r < 4; ++r) {
      #pragma unroll
      for (int m = 1; m < 16; m <<= 1) ps[r] += __shfl_xor(ps[r], m, 64);
      lrow[r] = lrow[r] * corr[r] + ps[r];
    }
    #pragma unroll
    for (int nt = 0; nt < 8; ++nt) {
      #pragma unroll
      for (int r = 0; r < 4; ++r) oacc[nt][r] *= corr[r];
    }

    // P -> LDS (D-layout) then re-read as A-fragments
    #pragma unroll
    for (int jt = 0; jt < 4; ++jt) {
      #pragma unroll
      for (int r = 0; r < 4; ++r)
        plds[wid][((lane >> 4) << 2) + r][jt * 16 + (lane & 15)] = f2bf(s[jt][r]);
    }
    __syncthreads();
    short8v pa[2];
    #pragma unroll
    for (int kk = 0; kk < 2; ++kk)
      pa[kk] = *reinterpret_cast<const short8v*>(
          &plds[wid][lane & 15][kk * 32 + ((lane >> 4) << 3)]);
    #pragma unroll
    for (int nt = 0; nt < 8; ++nt) {
      #pragma unroll
      for (int kk = 0; kk < 2; ++kk) {
        short8v vf = *reinterpret_cast<const short8v*>(
            &vlds[nt * 16 + (lane & 15)][kk * 32 + ((lane >> 4) << 3)]);
        oacc[nt] = mfma_bf16(pa[kk], vf, oacc[nt]);
      }
    }
  }

  short* ob = o + (size_t)b * NN * CC;
  #pragma unroll
  for (int nt = 0; nt < 8; ++nt) {
    #pragma unroll
    for (int r = 0; r < 4; ++r) {
      int row = qrow + ((lane >> 4) << 2) + r;
      ob[(size_t)row * CC + nt * 16 + (lane & 15)] = f2bf(oacc[nt][r] / lrow[r]);
    }
  }
}

// ---------------- launch -----------------------------------------------------
extern "C" void kernel_launch(void* const* d_in, const int* in_sizes, int n_in,
                              void* d_out, int out_size, void* d_ws, size_t ws_size,
                              hipStream_t stream) {
  (void)in_sizes; (void)n_in; (void)out_size; (void)ws_size;
  const float* x   = (const float*)d_in[0];
  const float* gsc = (const float*)d_in[1];
  const float* gbi = (const float*)d_in[2];
  const float* wq  = (const float*)d_in[3];
  const float* bq  = (const float*)d_in[4];
  const float* wk  = (const float*)d_in[5];
  const float* bk  = (const float*)d_in[6];
  const float* wv  = (const float*)d_in[7];
  const float* bv  = (const float*)d_in[8];
  const float* wo  = (const float*)d_in[9];
  const float* bo  = (const float*)d_in[10];
  float* out = (float*)d_out;

  char* ws = (char*)d_ws;
  short* wT   = (short*)(ws);                       // 4*16384 bf16
  float* bqs  = (float*)(ws + 131072);              // 128 f32 (scaled bq)
  float* mean = (float*)(ws + 131584);              // 256 f32
  float* rstd = (float*)(ws + 132608);              // 256 f32
  short* h    = (short*)(ws + 133632);              // [32768][128] bf16
  short* qb   = (short*)(ws + 133632 + 1 * 8388608);
  short* kb   = (short*)(ws + 133632 + 2 * 8388608);
  short* vtb  = (short*)(ws + 133632 + 3 * 8388608); // [B][C][N] bf16
  short* obuf = (short*)(ws + 133632 + 4 * 8388608);

  convw_k<<<256, 256, 0, stream>>>(wq, wk, wv, wo, bq, wT, bqs);
  gnstat_k<<<256, 256, 0, stream>>>(x, mean, rstd);
  gnapply_k<<<4096, 256, 0, stream>>>(x, mean, rstd, gsc, gbi, h);
  proj_k<0><<<512, 256, 0, stream>>>(h, wT,           bqs, qb);
  proj_k<0><<<512, 256, 0, stream>>>(h, wT + 16384,   bk,  kb);
  proj_k<1><<<512, 256, 0, stream>>>(h, wT + 32768,   bv,  vtb);
  attn_k<<<512, 256, 0, stream>>>(qb, kb, vtb, obuf);
  projo_k<<<512, 256, 0, stream>>>(obuf, wT + 49152, bo, x, out);
}

// Round 2
// 147.808 us; speedup vs baseline: 2.2995x; 2.2995x over previous
//
#include <hip/hip_runtime.h>
#include <hip/hip_bf16.h>

#define NN 4096
#define CC 128
#define SCALE 0.088388347648318447f   // 128^-0.5
#define LOG2E 1.4426950408889634f

typedef __attribute__((ext_vector_type(8))) short short8v;
typedef __attribute__((ext_vector_type(4))) float f32x4;
typedef __attribute__((ext_vector_type(16))) float f32x16;

#define Z16 {0.f,0.f,0.f,0.f,0.f,0.f,0.f,0.f,0.f,0.f,0.f,0.f,0.f,0.f,0.f,0.f}

__device__ __forceinline__ short f2bf(float f) {
  unsigned u = __float_as_uint(f);
  u = (u + 0x7FFFu + ((u >> 16) & 1u)) >> 16;
  return (short)u;
}
__device__ __forceinline__ float bf2f(short s) {
  return __uint_as_float(((unsigned)(unsigned short)s) << 16);
}
__device__ __forceinline__ unsigned pk2bf(float lo, float hi) {
  unsigned r;
  asm("v_cvt_pk_bf16_f32 %0, %1, %2" : "=v"(r) : "v"(lo), "v"(hi));
  return r;
}
__device__ __forceinline__ f32x4 mfma16(short8v a, short8v b, f32x4 c) {
  return __builtin_amdgcn_mfma_f32_16x16x32_bf16(a, b, c, 0, 0, 0);
}
__device__ __forceinline__ f32x16 mfma32(short8v a, short8v b, f32x16 c) {
  return __builtin_amdgcn_mfma_f32_32x32x16_bf16(a, b, c, 0, 0, 0);
}
__device__ __forceinline__ void gload16(const void* g, void* l) {
  __builtin_amdgcn_global_load_lds(
      (const __attribute__((address_space(1))) unsigned*)g,
      (__attribute__((address_space(3))) unsigned*)l, 16, 0, 0);
}

// ---------------- weight convert: wT[n][k] bf16; SCALE*LOG2E folded into wq/bq
__global__ __launch_bounds__(256) void convw_k(
    const float* __restrict__ wq, const float* __restrict__ wk,
    const float* __restrict__ wv, const float* __restrict__ wo,
    const float* __restrict__ bq, short* __restrict__ wT,
    float* __restrict__ bqs) {
  int gid = blockIdx.x * 256 + threadIdx.x;   // 4*16384
  int widx = gid >> 14, e = gid & 16383;
  int kk = e >> 7, n = e & 127;
  const float* src = (widx == 0) ? wq : (widx == 1) ? wk : (widx == 2) ? wv : wo;
  float v = src[kk * 128 + n];
  if (widx == 0) v *= SCALE * LOG2E;
  wT[widx * 16384 + n * 128 + kk] = f2bf(v);
  if (gid < 128) bqs[gid] = bq[gid] * SCALE * LOG2E;
}

// ---------------- groupnorm stats ------------------------------------------
__global__ __launch_bounds__(256) void gnstat_k(const float* __restrict__ x,
    float* __restrict__ mean, float* __restrict__ rstd) {
  int bg = blockIdx.x;                         // b*32+g
  const float* xp = x + (size_t)(bg >> 5) * NN * CC + (bg & 31) * 4;
  float s = 0.f, ss = 0.f;
  for (int n = threadIdx.x; n < NN; n += 256) {
    float4 v = *reinterpret_cast<const float4*>(xp + (size_t)n * CC);
    s  += v.x + v.y + v.z + v.w;
    ss += v.x * v.x + v.y * v.y + v.z * v.z + v.w * v.w;
  }
  #pragma unroll
  for (int m = 1; m < 64; m <<= 1) {
    s += __shfl_xor(s, m, 64);
    ss += __shfl_xor(ss, m, 64);
  }
  __shared__ float rs[4], rss[4];
  int wid = threadIdx.x >> 6;
  if ((threadIdx.x & 63) == 0) { rs[wid] = s; rss[wid] = ss; }
  __syncthreads();
  if (threadIdx.x == 0) {
    s = rs[0] + rs[1] + rs[2] + rs[3];
    ss = rss[0] + rss[1] + rss[2] + rss[3];
    float mu = s * (1.f / 16384.f);
    float var = ss * (1.f / 16384.f) - mu * mu;
    mean[bg] = mu;
    rstd[bg] = rsqrtf(var + 1e-6f);
  }
}

// ---------------- groupnorm apply -> h bf16 ---------------------------------
__global__ __launch_bounds__(256) void gnapply_k(const float* __restrict__ x,
    const float* __restrict__ mean, const float* __restrict__ rstd,
    const float* __restrict__ gsc, const float* __restrict__ gbi,
    short* __restrict__ h) {
  int idx = blockIdx.x * 256 + threadIdx.x;    // row*32 + g
  int row = idx >> 5, g = idx & 31;
  int bg = ((row >> 12) << 5) | g;
  float4 v  = *reinterpret_cast<const float4*>(x + (size_t)row * CC + g * 4);
  float4 sc = *reinterpret_cast<const float4*>(gsc + g * 4);
  float4 bi = *reinterpret_cast<const float4*>(gbi + g * 4);
  float mu = mean[bg], r = rstd[bg];
  short4 o;
  o.x = f2bf((v.x - mu) * r * sc.x + bi.x);
  o.y = f2bf((v.y - mu) * r * sc.y + bi.y);
  o.z = f2bf((v.z - mu) * r * sc.z + bi.z);
  o.w = f2bf((v.w - mu) * r * sc.w + bi.w);
  *reinterpret_cast<short4*>(h + (size_t)row * CC + g * 4) = o;
}

// ---------------- projection GEMM: out = h @ W + b --------------------------
template <int TRANS>
__global__ __launch_bounds__(256) void proj_k(const short* __restrict__ h,
    const short* __restrict__ wT, const float* __restrict__ bias,
    short* __restrict__ out) {
  __shared__ short wlds[128][136];
  int lane = threadIdx.x & 63, wid = threadIdx.x >> 6;
  for (int i = threadIdx.x; i < 2048; i += 256) {
    int n = i >> 4, kk = (i & 15) << 3;
    *reinterpret_cast<short8v*>(&wlds[n][kk]) =
        *reinterpret_cast<const short8v*>(wT + n * 128 + kk);
  }
  int row0 = blockIdx.x * 64 + wid * 16;
  int arow = row0 + (lane & 15);
  short8v a[4];
  #pragma unroll
  for (int dt = 0; dt < 4; ++dt)
    a[dt] = *reinterpret_cast<const short8v*>(
        h + (size_t)arow * 128 + dt * 32 + ((lane >> 4) << 3));
  __syncthreads();
  f32x4 zero = {0.f, 0.f, 0.f, 0.f};
  f32x4 acc[8];
  #pragma unroll
  for (int nt = 0; nt < 8; ++nt) acc[nt] = zero;
  #pragma unroll
  for (int nt = 0; nt < 8; ++nt) {
    #pragma unroll
    for (int kk = 0; kk < 4; ++kk) {
      short8v b = *reinterpret_cast<const short8v*>(
          &wlds[nt * 16 + (lane & 15)][kk * 32 + ((lane >> 4) << 3)]);
      acc[nt] = mfma16(a[kk], b, acc[nt]);
    }
  }
  #pragma unroll
  for (int nt = 0; nt < 8; ++nt) {
    #pragma unroll
    for (int r = 0; r < 4; ++r) {
      int row = row0 + ((lane >> 4) << 2) + r;
      int col = nt * 16 + (lane & 15);
      float v = acc[nt][r] + bias[col];
      if (TRANS) {
        int b_ = row >> 12, n = row & 4095;
        out[((size_t)b_ * 128 + col) * 4096 + n] = f2bf(v);
      } else {
        out[(size_t)row * 128 + col] = f2bf(v);
      }
    }
  }
}

// ---------------- output projection + bias + residual (fp32 out) ------------
__global__ __launch_bounds__(256) void projo_k(const short* __restrict__ o,
    const short* __restrict__ wT, const float* __restrict__ bias,
    const float* __restrict__ x, float* __restrict__ out) {
  __shared__ short wlds[128][136];
  int lane = threadIdx.x & 63, wid = threadIdx.x >> 6;
  for (int i = threadIdx.x; i < 2048; i += 256) {
    int n = i >> 4, kk = (i & 15) << 3;
    *reinterpret_cast<short8v*>(&wlds[n][kk]) =
        *reinterpret_cast<const short8v*>(wT + n * 128 + kk);
  }
  int row0 = blockIdx.x * 64 + wid * 16;
  int arow = row0 + (lane & 15);
  short8v a[4];
  #pragma unroll
  for (int dt = 0; dt < 4; ++dt)
    a[dt] = *reinterpret_cast<const short8v*>(
        o + (size_t)arow * 128 + dt * 32 + ((lane >> 4) << 3));
  __syncthreads();
  f32x4 zero = {0.f, 0.f, 0.f, 0.f};
  f32x4 acc[8];
  #pragma unroll
  for (int nt = 0; nt < 8; ++nt) acc[nt] = zero;
  #pragma unroll
  for (int nt = 0; nt < 8; ++nt) {
    #pragma unroll
    for (int kk = 0; kk < 4; ++kk) {
      short8v b = *reinterpret_cast<const short8v*>(
          &wlds[nt * 16 + (lane & 15)][kk * 32 + ((lane >> 4) << 3)]);
      acc[nt] = mfma16(a[kk], b, acc[nt]);
    }
  }
  #pragma unroll
  for (int nt = 0; nt < 8; ++nt) {
    #pragma unroll
    for (int r = 0; r < 4; ++r) {
      int row = row0 + ((lane >> 4) << 2) + r;
      int col = nt * 16 + (lane & 15);
      out[(size_t)row * 128 + col] =
          acc[nt][r] + bias[col] + x[(size_t)row * 128 + col];
    }
  }
}

// ---------------- flash attention v2: 8 warps, 32x32x16, swapped QK^T -------
// grid = 128*S blocks of 512 thr; each block: 256 q-rows, KV range NN/S.
// S^T = mfma(K,Q) -> lane holds 32 k-vals for q=lane&31 -> in-register softmax.
// K LDS [64][256B], V^T LDS [128][128B], both XOR-swizzled (byte^=(row&7)<<4),
// staged via global_load_lds (linear dest, pre-swizzled global source).
template <int S>
__global__ __launch_bounds__(512, 2) void attn2_k(
    const short* __restrict__ q, const short* __restrict__ k,
    const short* __restrict__ vt, short* __restrict__ opart,
    float* __restrict__ ms, float* __restrict__ ls) {
  constexpr int KVLEN = NN / S;
  constexpr int NIT = KVLEN / 64;
  __shared__ short8v smem_v[4096];             // 64 KiB: 2 x (16K K + 16K V)
  char* smem = (char*)smem_v;
  const int tid = threadIdx.x;
  const int lane = tid & 63, warp = tid >> 6;
  const int hh = lane >> 5, ql = lane & 31;
  const int split = (S == 2) ? ((int)blockIdx.x & 1) : 0;
  const int qb_lin = (S == 2) ? ((int)blockIdx.x >> 1) : (int)blockIdx.x;
  const int b = qb_lin >> 4, qblk = qb_lin & 15;
  const int kv0 = split * KVLEN;

  const size_t bqko = (size_t)b * NN * CC;
  short8v qf[8];
  {
    int qrow = qblk * 256 + warp * 32 + ql;
    const short* qp = q + bqko + (size_t)qrow * CC + hh * 8;
    #pragma unroll
    for (int dc = 0; dc < 8; ++dc)
      qf[dc] = *reinterpret_cast<const short8v*>(qp + dc * 16);
  }
  const char* kg = (const char*)(k + bqko);
  const char* vg = (const char*)(vt + (size_t)b * CC * NN);
  // staging geometry (chunk c adds 32 rows (K) / 64 rows (V); row&7 unaffected)
  const int kr = tid >> 4;
  const int ksw = 16 * ((tid & 15) ^ (kr & 7));
  const int vd = tid >> 3;
  const int vsw = 16 * ((tid & 7) ^ (vd & 7));

  auto stage = [&](int buf, int it) {
    const int kvo = kv0 + it * 64;
    char* base = smem + buf * 32768;
    #pragma unroll
    for (int c = 0; c < 2; ++c) {
      gload16(kg + (size_t)(kvo + c * 32 + kr) * 256 + ksw,
              base + c * 8192 + warp * 1024);
      gload16(vg + (size_t)(c * 64 + vd) * 8192 + (size_t)kvo * 2 + vsw,
              base + 16384 + c * 8192 + warp * 1024);
    }
  };

  f32x16 oacc[4] = {Z16, Z16, Z16, Z16};
  float m_run = -1e30f, l_run = 0.f;

  stage(0, 0);
  asm volatile("s_waitcnt vmcnt(0)" ::: "memory");
  __builtin_amdgcn_s_barrier();

  const int swz = (ql & 7) << 4;
  for (int it = 0; it < NIT; ++it) {
    const int cur = it & 1;
    if (it + 1 < NIT) stage(cur ^ 1, it + 1);

    // S^T = K x Q  (64k x 32q per warp, 2 tiles)
    const char* kb_ = smem + cur * 32768;
    f32x16 sT[2] = {Z16, Z16};
    #pragma unroll
    for (int kt = 0; kt < 2; ++kt) {
      const char* kr_p = kb_ + (32 * kt + ql) * 256;
      #pragma unroll
      for (int dc = 0; dc < 8; ++dc) {
        short8v kf = *reinterpret_cast<const short8v*>(
            kr_p + ((32 * dc + 16 * hh) ^ swz));
        sT[kt] = mfma32(kf, qf[dc], sT[kt]);
      }
    }

    // online softmax, in-register (q = ql; partner lane ql^32 holds other k's)
    float pmax = -1e30f;
    #pragma unroll
    for (int kt = 0; kt < 2; ++kt)
      #pragma unroll
      for (int r = 0; r < 16; ++r) pmax = fmaxf(pmax, sT[kt][r]);
    pmax = fmaxf(pmax, __shfl_xor(pmax, 32));
    if (!__all(pmax <= m_run + 8.f)) {          // defer-max, THR=8 (log2 units)
      float mn = fmaxf(m_run, pmax);
      float corr = exp2f(m_run - mn);
      m_run = mn; l_run *= corr;
      #pragma unroll
      for (int r = 0; r < 16; ++r) {
        float cr = __shfl(corr, (r & 3) + 8 * (r >> 2) + 4 * hh);
        #pragma unroll
        for (int dt = 0; dt < 4; ++dt) oacc[dt][r] *= cr;
      }
    }
    float rsum = 0.f;
    #pragma unroll
    for (int kt = 0; kt < 2; ++kt)
      #pragma unroll
      for (int r = 0; r < 16; ++r) {
        float p = exp2f(sT[kt][r] - m_run);
        sT[kt][r] = p; rsum += p;
      }
    rsum += __shfl_xor(rsum, 32);
    l_run += rsum;

    // P -> PV A-frags in-register (cvt_pk + lane^32 exchange), then PV
    const char* vb_ = smem + cur * 32768 + 16384;
    #pragma unroll
    for (int st = 0; st < 4; ++st) {
      const int kt = st >> 1, rb = 8 * (st & 1);
      unsigned w0, w1, w2, w3;
      {
        unsigned xlo = pk2bf(sT[kt][rb + 0], sT[kt][rb + 1]);
        unsigned xhi = pk2bf(sT[kt][rb + 4], sT[kt][rb + 5]);
        unsigned xlx = (unsigned)__shfl_xor((int)xlo, 32);
        unsigned xhx = (unsigned)__shfl_xor((int)xhi, 32);
        w0 = hh ? xhx : xlo;
        w2 = hh ? xhi : xlx;
      }
      {
        unsigned xlo = pk2bf(sT[kt][rb + 2], sT[kt][rb + 3]);
        unsigned xhi = pk2bf(sT[kt][rb + 6], sT[kt][rb + 7]);
        unsigned xlx = (unsigned)__shfl_xor((int)xlo, 32);
        unsigned xhx = (unsigned)__shfl_xor((int)xhi, 32);
        w1 = hh ? xhx : xlo;
        w3 = hh ? xhi : xlx;
      }
      union { unsigned u[4]; short8v v; } pu;
      pu.u[0] = w0; pu.u[1] = w1; pu.u[2] = w2; pu.u[3] = w3;
      #pragma unroll
      for (int dt = 0; dt < 4; ++dt) {
        const char* vr_p = vb_ + (32 * dt + ql) * 128;
        short8v vf = *reinterpret_cast<const short8v*>(
            vr_p + ((32 * st + 16 * hh) ^ swz));
        oacc[dt] = mfma32(pu.v, vf, oacc[dt]);
      }
    }

    asm volatile("s_waitcnt vmcnt(0)" ::: "memory");
    __builtin_amdgcn_s_barrier();
  }

  // epilogue: normalized bf16 partial + (m,l)
  float rinv = 1.f / l_run;
  short* op = opart + ((size_t)(split * 8 + b) * NN + qblk * 256 + warp * 32) * CC;
  #pragma unroll
  for (int r = 0; r < 16; ++r) {
    int qp = (r & 3) + 8 * (r >> 2) + 4 * hh;
    float ri = __shfl(rinv, qp);
    #pragma unroll
    for (int dt = 0; dt < 4; ++dt)
      op[(size_t)qp * CC + 32 * dt + ql] = f2bf(oacc[dt][r] * ri);
  }
  if (hh == 0) {
    size_t ix = (size_t)(split * 8 + b) * NN + qblk * 256 + warp * 32 + ql;
    ms[ix] = m_run; ls[ix] = l_run;
  }
}

// ---------------- combine two KV-split partials -----------------------------
__global__ __launch_bounds__(256) void comb_k(const short* __restrict__ opart,
    const float* __restrict__ ms, const float* __restrict__ ls,
    short* __restrict__ obuf) {
  int gid = blockIdx.x * 256 + threadIdx.x;    // 32768*16
  int row = gid >> 4, cg = (gid & 15) << 3;
  float m0 = ms[row], m1 = ms[row + 32768];
  float l0 = ls[row], l1 = ls[row + 32768];
  float M = fmaxf(m0, m1);
  float a0 = exp2f(m0 - M) * l0, a1 = exp2f(m1 - M) * l1;
  float inv = 1.f / (a0 + a1);
  a0 *= inv; a1 *= inv;
  short8v v0 = *reinterpret_cast<const short8v*>(opart + (size_t)row * CC + cg);
  short8v v1 = *reinterpret_cast<const short8v*>(
      opart + ((size_t)row + 32768) * CC + cg);
  short8v o;
  #pragma unroll
  for (int e = 0; e < 8; ++e)
    o[e] = f2bf(bf2f(v0[e]) * a0 + bf2f(v1[e]) * a1);
  *reinterpret_cast<short8v*>(obuf + (size_t)row * CC + cg) = o;
}

// ---------------- launch -----------------------------------------------------
extern "C" void kernel_launch(void* const* d_in, const int* in_sizes, int n_in,
                              void* d_out, int out_size, void* d_ws, size_t ws_size,
                              hipStream_t stream) {
  (void)in_sizes; (void)n_in; (void)out_size;
  const float* x   = (const float*)d_in[0];
  const float* gsc = (const float*)d_in[1];
  const float* gbi = (const float*)d_in[2];
  const float* wq  = (const float*)d_in[3];
  const float* bq  = (const float*)d_in[4];
  const float* wk  = (const float*)d_in[5];
  const float* bk  = (const float*)d_in[6];
  const float* wv  = (const float*)d_in[7];
  const float* bv  = (const float*)d_in[8];
  const float* wo  = (const float*)d_in[9];
  const float* bo  = (const float*)d_in[10];
  float* out = (float*)d_out;

  char* ws = (char*)d_ws;
  constexpr size_t OFF_WT   = 0;                  // 131072
  constexpr size_t OFF_BQS  = 131072;             // 512
  constexpr size_t OFF_MEAN = 131584;             // 1024
  constexpr size_t OFF_RSTD = 132608;             // 1024
  constexpr size_t OFF_MS   = 133632;             // 262144
  constexpr size_t OFF_LS   = OFF_MS + 262144;    // 395776 + 262144 = 657920
  constexpr size_t OFF_QB   = 658432;             // 8 MiB (reused as obuf if S==2)
  constexpr size_t OFF_KB   = OFF_QB + 8388608;
  constexpr size_t OFF_VT   = OFF_KB + 8388608;
  constexpr size_t OFF_X    = OFF_VT + 8388608;   // h (8M); opart (S*8M)
  constexpr size_t NEED2    = OFF_X + 16777216;   // 42601472

  short* wT   = (short*)(ws + OFF_WT);
  float* bqs  = (float*)(ws + OFF_BQS);
  float* mean = (float*)(ws + OFF_MEAN);
  float* rstd = (float*)(ws + OFF_RSTD);
  float* ms   = (float*)(ws + OFF_MS);
  float* ls   = (float*)(ws + OFF_LS);
  short* qb   = (short*)(ws + OFF_QB);
  short* kb   = (short*)(ws + OFF_KB);
  short* vtb  = (short*)(ws + OFF_VT);
  short* h    = (short*)(ws + OFF_X);
  short* opart= (short*)(ws + OFF_X);
  const int S = (ws_size >= NEED2) ? 2 : 1;
  short* obuf = (S == 2) ? qb : opart;

  convw_k<<<256, 256, 0, stream>>>(wq, wk, wv, wo, bq, wT, bqs);
  gnstat_k<<<256, 256, 0, stream>>>(x, mean, rstd);
  gnapply_k<<<4096, 256, 0, stream>>>(x, mean, rstd, gsc, gbi, h);
  proj_k<0><<<512, 256, 0, stream>>>(h, wT,         bqs, qb);
  proj_k<0><<<512, 256, 0, stream>>>(h, wT + 16384, bk,  kb);
  proj_k<1><<<512, 256, 0, stream>>>(h, wT + 32768, bv,  vtb);
  if (S == 2) {
    attn2_k<2><<<256, 512, 0, stream>>>(qb, kb, vtb, opart, ms, ls);
    comb_k<<<2048, 256, 0, stream>>>(opart, ms, ls, obuf);
  } else {
    attn2_k<1><<<128, 512, 0, stream>>>(qb, kb, vtb, opart, ms, ls);
  }
  projo_k<<<512, 256, 0, stream>>>(obuf, wT + 49152, bo, x, out);
}